// Round 3
// baseline (536.324 us; speedup 1.0000x reference)
//
#include <hip/hip_runtime.h>

#define ADAGRAD_EPS 1e-10f

typedef float f4 __attribute__((ext_vector_type(4)));

// Workspace layout: head[V], next[N], tlist[N], cnt[1].
// head = -1 via hipMemsetAsync(0xFF); cnt = 0 via hipMemsetAsync(0).
// build_lists compacts the DISTINCT touched rows into tlist using the
// first-toucher property of atomicExch (exactly one thread per index sees
// prev == -1). atomicAdd(cnt,1) is wave-coalesced by the compiler (m20).

__global__ void build_lists_kernel(const int* __restrict__ idx,
                                   const int* __restrict__ vc_p,
                                   int* __restrict__ head,
                                   int* __restrict__ next,
                                   int* __restrict__ tlist,
                                   int* __restrict__ cnt) {
    int vc = *vc_p;
    int r = blockIdx.x * blockDim.x + threadIdx.x;
    if (r >= vc) return;
    int i = idx[r];
    int prev = atomicExch(&head[i], r);
    next[r] = prev;
    if (prev < 0) {                    // first toucher of row i
        int slot = atomicAdd(cnt, 1);
        tlist[slot] = i;
    }
}

// Branch-free streaming copy: out_w = w, out_m = m. One f4 per thread per
// stream (32 B read + 32 B write per thread). This is the same access
// pattern as the rocclr fill kernels, which sustain 6.4 TB/s here.
__global__ __launch_bounds__(256) void copy_kernel(
        const f4* __restrict__ w4,
        const f4* __restrict__ m4,
        f4* __restrict__ ow4,
        f4* __restrict__ om4,
        int n4) {
    int i = blockIdx.x * blockDim.x + threadIdx.x;
    if (i >= n4) return;
    ow4[i] = w4[i];
    om4[i] = m4[i];
}

// Sparse update over the compacted touched-row list only. 8 lanes per row,
// 2 f4 per lane. Dense waves (every lane belongs to a touched row); the
// copy pass already wrote these rows, we overwrite (WAW ordered by stream).
__global__ __launch_bounds__(256) void update_kernel(
        const f4* __restrict__ g4,
        const f4* __restrict__ w4,
        const f4* __restrict__ m4,
        const int* __restrict__ head,
        const int* __restrict__ next,
        const int* __restrict__ tlist,
        const int* __restrict__ cnt,
        const float* __restrict__ lr_p,
        f4* __restrict__ ow4,
        f4* __restrict__ om4) {
    int t = blockIdx.x * blockDim.x + threadIdx.x;
    int s = t >> 3;
    if (s >= *cnt) return;            // broadcast scalar load, cheap exit
    int v = tlist[s];
    int d2 = (t & 7) << 1;
    int off = v * 16 + d2;            // f4 units; max 8M -> fits int

    int r = head[v];                  // guaranteed >= 0
    f4 w0 = w4[off];
    f4 w1 = w4[off + 1];
    f4 m0 = m4[off];
    f4 m1 = m4[off + 1];
    float lr = *lr_p;

    f4 s10 = {0.f, 0.f, 0.f, 0.f};
    f4 s11 = s10, s20 = s10, s21 = s10;
    while (r >= 0) {
        int go = r * 16 + d2;
        f4 g0 = g4[go];
        f4 g1 = g4[go + 1];
        r = next[r];                  // issue before FMAs
        s10 += g0; s20 += g0 * g0;
        s11 += g1; s21 += g1 * g1;
    }

    f4 mn0 = m0 + s20;
    f4 mn1 = m1 + s21;
    om4[off]     = mn0;
    om4[off + 1] = mn1;

    f4 wn0, wn1;
    wn0.x = w0.x - lr * s10.x / (sqrtf(mn0.x) + ADAGRAD_EPS);
    wn0.y = w0.y - lr * s10.y / (sqrtf(mn0.y) + ADAGRAD_EPS);
    wn0.z = w0.z - lr * s10.z / (sqrtf(mn0.z) + ADAGRAD_EPS);
    wn0.w = w0.w - lr * s10.w / (sqrtf(mn0.w) + ADAGRAD_EPS);
    wn1.x = w1.x - lr * s11.x / (sqrtf(mn1.x) + ADAGRAD_EPS);
    wn1.y = w1.y - lr * s11.y / (sqrtf(mn1.y) + ADAGRAD_EPS);
    wn1.z = w1.z - lr * s11.z / (sqrtf(mn1.z) + ADAGRAD_EPS);
    wn1.w = w1.w - lr * s11.w / (sqrtf(mn1.w) + ADAGRAD_EPS);
    ow4[off]     = wn0;
    ow4[off + 1] = wn1;
}

extern "C" void kernel_launch(void* const* d_in, const int* in_sizes, int n_in,
                              void* d_out, int out_size, void* d_ws, size_t ws_size,
                              hipStream_t stream) {
    const float* g   = (const float*)d_in[0];  // [N, 64]
    const float* w   = (const float*)d_in[1];  // [V, 64]
    const float* m   = (const float*)d_in[2];  // [V, 64]
    const int*   idx = (const int*)d_in[3];    // [N]
    const float* lr  = (const float*)d_in[4];  // scalar
    const int*   vc  = (const int*)d_in[5];    // scalar

    long long ND = in_sizes[0];        // N*64
    long long VD = in_sizes[1];        // V*64
    int N = (int)(ND / 64);
    int V = (int)(VD / 64);

    float* out_w = (float*)d_out;
    float* out_m = (float*)d_out + VD;

    int* head  = (int*)d_ws;           // V ints
    int* next  = head + V;             // N ints
    int* tlist = next + N;             // N ints (worst case all distinct)
    int* cnt   = tlist + N;            // 1 int

    hipMemsetAsync(head, 0xFF, (size_t)V * sizeof(int), stream);  // -1
    hipMemsetAsync(cnt, 0, sizeof(int), stream);

    build_lists_kernel<<<(N + 255) / 256, 256, 0, stream>>>(
        idx, vc, head, next, tlist, cnt);

    int n4 = (int)(VD / 4);            // 8M f4 elements per buffer
    copy_kernel<<<(n4 + 255) / 256, 256, 0, stream>>>(
        (const f4*)w, (const f4*)m, (f4*)out_w, (f4*)out_m, n4);

    // Worst case: all vc rows distinct -> N*8 threads covers it.
    long long upd_threads = (long long)N * 8;
    update_kernel<<<(int)((upd_threads + 255) / 256), 256, 0, stream>>>(
        (const f4*)g, (const f4*)w, (const f4*)m,
        head, next, tlist, cnt, lr, (f4*)out_w, (f4*)out_m);
}

// Round 6
// 465.334 us; speedup vs baseline: 1.1526x; 1.1526x over previous
//
#include <hip/hip_runtime.h>

#define ADAGRAD_EPS 1e-10f

typedef float f4 __attribute__((ext_vector_type(4)));

// Per-index linked lists over gradient rows: head[V], next[N] in workspace.
// head = -1 via hipMemsetAsync(0xFF) -- no init kernel launch.
// R0-R3 ledger: fused 16-lane temporal kernel is best (467.6); NT stores
// regress (~+15); copy+compact-update split regresses (+50). This round:
// R0 structure + 2 rows per thread for doubled per-thread MLP.
// R5 bug fixed: copy gate was (r0|r1)<0 ("either untouched"); must be
// (r0&r1)<0 ("both untouched" -- sign bit of AND).

__global__ void build_lists_kernel(const int* __restrict__ idx,
                                   const int* __restrict__ vc_p,
                                   int* __restrict__ head,
                                   int* __restrict__ next) {
    int vc = *vc_p;
    int r = blockIdx.x * blockDim.x + threadIdx.x;
    if (r >= vc) return;
    int i = idx[r];
    next[r] = atomicExch(&head[i], r);
}

// 16 lanes per vocab row (1 f4 = 16 B per lane per stream), wave covers 4
// consecutive rows -> every w/m/ow/om access is a contiguous 1 KB per wave
// instruction. Each thread additionally owns a second row H away:
// 4 independent loads + 4 independent stores + 2 independent chains in
// flight per thread (2x the MLP of R0's kernel, same coalescing).
__global__ __launch_bounds__(256) void apply_kernel(
        const f4* __restrict__ g4,
        const f4* __restrict__ w4,
        const f4* __restrict__ m4,
        const int* __restrict__ head,
        const int* __restrict__ next,
        const float* __restrict__ lr_p,
        f4* __restrict__ ow4,
        f4* __restrict__ om4,
        int V, int H) {
    int t = blockIdx.x * blockDim.x + threadIdx.x;
    int v0 = t >> 4;
    if (v0 >= H) return;
    int d = t & 15;
    int v1 = v0 + H;
    bool has1 = (v1 < V);

    int off0 = v0 * 16 + d;            // f4 units; max 8M -> fits int
    int off1 = v1 * 16 + d;

    int r0 = head[v0];                 // gate loads first, in flight early
    int r1 = has1 ? head[v1] : -1;

    f4 z = {0.f, 0.f, 0.f, 0.f};
    f4 w0 = w4[off0];
    f4 m0 = m4[off0];
    f4 w1 = has1 ? w4[off1] : z;
    f4 m1 = has1 ? m4[off1] : z;

    float lr = *lr_p;                  // hides under everything below

    if ((r0 & r1) < 0) {               // BOTH rows untouched: pure copy
        ow4[off0] = w0;
        om4[off0] = m0;
        if (has1) { ow4[off1] = w1; om4[off1] = m1; }
        return;
    }

    f4 a1 = z, a2 = z;                 // row v0: sum g, sum g^2
    f4 b1 = z, b2 = z;                 // row v1
    while (r0 >= 0 || r1 >= 0) {       // interleave both chains for MLP
        if (r0 >= 0) {
            f4 g0 = g4[r0 * 16 + d];
            r0 = next[r0];
            a1 += g0; a2 += g0 * g0;
        }
        if (r1 >= 0) {
            f4 g1 = g4[r1 * 16 + d];
            r1 = next[r1];
            b1 += g1; b2 += g1 * g1;
        }
    }

    // r==-1 chains contribute zero sums: mn=m, wn=w exactly (lr*0/denom=0),
    // so the update path is correct for mixed touched/untouched pairs.
    f4 mn0 = m0 + a2;
    om4[off0] = mn0;
    f4 wn0;
    wn0.x = w0.x - lr * a1.x / (sqrtf(mn0.x) + ADAGRAD_EPS);
    wn0.y = w0.y - lr * a1.y / (sqrtf(mn0.y) + ADAGRAD_EPS);
    wn0.z = w0.z - lr * a1.z / (sqrtf(mn0.z) + ADAGRAD_EPS);
    wn0.w = w0.w - lr * a1.w / (sqrtf(mn0.w) + ADAGRAD_EPS);
    ow4[off0] = wn0;

    if (has1) {
        f4 mn1 = m1 + b2;
        om4[off1] = mn1;
        f4 wn1;
        wn1.x = w1.x - lr * b1.x / (sqrtf(mn1.x) + ADAGRAD_EPS);
        wn1.y = w1.y - lr * b1.y / (sqrtf(mn1.y) + ADAGRAD_EPS);
        wn1.z = w1.z - lr * b1.z / (sqrtf(mn1.z) + ADAGRAD_EPS);
        wn1.w = w1.w - lr * b1.w / (sqrtf(mn1.w) + ADAGRAD_EPS);
        ow4[off1] = wn1;
    }
}

extern "C" void kernel_launch(void* const* d_in, const int* in_sizes, int n_in,
                              void* d_out, int out_size, void* d_ws, size_t ws_size,
                              hipStream_t stream) {
    const float* g   = (const float*)d_in[0];  // [N, 64]
    const float* w   = (const float*)d_in[1];  // [V, 64]
    const float* m   = (const float*)d_in[2];  // [V, 64]
    const int*   idx = (const int*)d_in[3];    // [N]
    const float* lr  = (const float*)d_in[4];  // scalar
    const int*   vc  = (const int*)d_in[5];    // scalar

    long long ND = in_sizes[0];        // N*64
    long long VD = in_sizes[1];        // V*64
    int N = (int)(ND / 64);
    int V = (int)(VD / 64);

    float* out_w = (float*)d_out;
    float* out_m = (float*)d_out + VD;

    int* head = (int*)d_ws;            // V ints
    int* next = head + V;              // N ints

    // head[v] = -1 for all v via DMA fill (0xFFFFFFFF == -1).
    hipMemsetAsync(head, 0xFF, (size_t)V * sizeof(int), stream);

    build_lists_kernel<<<(N + 255) / 256, 256, 0, stream>>>(idx, vc, head, next);

    int H = (V + 1) / 2;               // thread covers rows v and v+H
    long long apply_threads = (long long)H * 16;
    apply_kernel<<<(int)((apply_threads + 255) / 256), 256, 0, stream>>>(
        (const f4*)g, (const f4*)w, (const f4*)m,
        head, next, lr, (f4*)out_w, (f4*)out_m, V, H);
}